// Round 2
// baseline (348.773 us; speedup 1.0000x reference)
//
#include <hip/hip_runtime.h>

#define B_ 8
#define C_ 256
#define N_ 4096
#define LOG2E 1.44269504088896f
#define SHIFT 14.0f

typedef _Float16 half8 __attribute__((ext_vector_type(8)));
typedef _Float16 half4 __attribute__((ext_vector_type(4)));
typedef float floatx4 __attribute__((ext_vector_type(4)));

// ---------------- K0a: transpose-cast x[b][c][i] fp32 -> xT[b][i][c] fp16 ----
// v2: 16B global writes via LDS transpose (was 2B/lane scattered stores)
__global__ __launch_bounds__(256) void k_transpose(const float* __restrict__ x,
                                                   _Float16* __restrict__ xT) {
    __shared__ float tile[64][65];
    int i0 = blockIdx.x * 64;
    int c0 = blockIdx.y * 64;
    int b  = blockIdx.z;
    int t  = threadIdx.x;
    const float* xb = x + ((size_t)(b * C_ + c0)) * N_ + i0;
    int r4 = t >> 4;            // 0..15
    int c4 = (t & 15) * 4;      // i-offset 0..60
#pragma unroll
    for (int k = 0; k < 4; ++k) {
        int r = k * 16 + r4;    // c-row 0..63
        *(float4*)&tile[r][c4] = *(const float4*)&xb[(size_t)r * N_ + c4];
    }
    __syncthreads();
    _Float16* xTb = xT + ((size_t)(b * N_ + i0)) * C_ + c0;
    int i2 = t >> 2;            // i-row 0..63
#pragma unroll
    for (int g = 0; g < 2; ++g) {
        int ch = (t & 3) + g * 4;   // c-chunk 0..7 (8 halves each)
        half8 v;
#pragma unroll
        for (int j = 0; j < 8; ++j) v[j] = (_Float16)tile[ch * 8 + j][i2];
        *(half8*)&xTb[(size_t)i2 * C_ + ch * 8] = v;
    }
}

// ---------------- K0b: weight concat + fp16 cast: Wh[320][256], Bh[320] -----
__global__ __launch_bounds__(256) void k_wprep(const float* __restrict__ wq, const float* __restrict__ bq,
                                               const float* __restrict__ wk, const float* __restrict__ bk,
                                               const float* __restrict__ wv, const float* __restrict__ bv,
                                               _Float16* __restrict__ Wh, float* __restrict__ Bh) {
    int r = blockIdx.x;   // 0..319
    int t = threadIdx.x;  // 0..255
    const float* src;
    float bias;
    if (r < 32)      { src = wq + r * 256;        bias = bq[r]; }
    else if (r < 64) { src = wk + (r - 32) * 256; bias = bk[r - 32]; }
    else             { src = wv + (r - 64) * 256; bias = bv[r - 64]; }
    Wh[r * 256 + t] = (_Float16)src[t];
    if (t == 0) Bh[r] = bias;
}

// ---------------- K1: fused projection GEMM ---------------------------------
__global__ __launch_bounds__(256, 2) void k_proj(const _Float16* __restrict__ xT,
                                                 const _Float16* __restrict__ Wh,
                                                 const float* __restrict__ Bh,
                                                 _Float16* __restrict__ FG,
                                                 _Float16* __restrict__ V) {
    __shared__ _Float16 As[64 * 40] __attribute__((aligned(16)));
    __shared__ _Float16 Bs[320 * 40] __attribute__((aligned(16)));
    int id = blockIdx.x;
    int b  = id & 7;          // XCD-local batch
    int i0 = (id >> 3) * 64;
    int t = threadIdx.x;
    int w = t >> 6, lane = t & 63, col = lane & 15, q = lane >> 4;
    floatx4 acc[4][5];
#pragma unroll
    for (int mt = 0; mt < 4; ++mt)
#pragma unroll
        for (int nt = 0; nt < 5; ++nt) acc[mt][nt] = (floatx4){0.f, 0.f, 0.f, 0.f};
    const _Float16* xTb = xT + ((size_t)(b * N_ + i0)) * 256;
    for (int kc = 0; kc < 8; ++kc) {
        int k0 = kc * 32;
        {   // stage A tile: 64 rows x 32 k
            int i = t >> 2, part = t & 3;
            *(uint4*)&As[i * 40 + part * 8] = *(const uint4*)&xTb[(size_t)i * 256 + k0 + part * 8];
        }
#pragma unroll
        for (int rep = 0; rep < 5; ++rep) {  // stage B tile: 320 rows x 32 k
            int idx = t + rep * 256;
            int row = idx >> 2, part = idx & 3;
            *(uint4*)&Bs[row * 40 + part * 8] = *(const uint4*)&Wh[row * 256 + k0 + part * 8];
        }
        __syncthreads();
        half8 a[4], bf[5];
#pragma unroll
        for (int mt = 0; mt < 4; ++mt) a[mt] = *(const half8*)&As[(mt * 16 + col) * 40 + q * 8];
#pragma unroll
        for (int nt = 0; nt < 5; ++nt) bf[nt] = *(const half8*)&Bs[(w * 80 + nt * 16 + col) * 40 + q * 8];
#pragma unroll
        for (int mt = 0; mt < 4; ++mt)
#pragma unroll
            for (int nt = 0; nt < 5; ++nt)
                acc[mt][nt] = __builtin_amdgcn_mfma_f32_16x16x32_f16(a[mt], bf[nt], acc[mt][nt], 0, 0, 0);
        __syncthreads();
    }
#pragma unroll
    for (int nt = 0; nt < 5; ++nt) {
        int n = w * 80 + nt * 16 + col;
        float bias = Bh[n];
        if (n < 64) {
#pragma unroll
            for (int mt = 0; mt < 4; ++mt)
#pragma unroll
                for (int r = 0; r < 4; ++r) {
                    int i = i0 + mt * 16 + q * 4 + r;
                    FG[((size_t)(b * N_ + i)) * 64 + n] = (_Float16)(acc[mt][nt][r] + bias);
                }
        } else {
            int c = n - 64;
            _Float16* Vp = V + ((size_t)(b * C_ + c)) * N_ + i0;
#pragma unroll
            for (int mt = 0; mt < 4; ++mt) {
                half4 v4;
#pragma unroll
                for (int r = 0; r < 4; ++r) v4[r] = (_Float16)(acc[mt][nt][r] + bias);
                *(half4*)&Vp[mt * 16 + q * 4] = v4;
            }
        }
    }
}

// ---------------- K2: fused attention v2 ------------------------------------
// 512 thr (8 waves), j-tile 128, 1 block/CU. K/V/Q frags direct from global
// (L2-resident via b=id&7 XCD pinning); only P goes through LDS, double-
// buffered -> ONE barrier per i-iteration.
__global__ __launch_bounds__(512, 2) void k_attn(const _Float16* __restrict__ FG,
                                                 const _Float16* __restrict__ V,
                                                 const float* __restrict__ x,
                                                 const float* __restrict__ gptr,
                                                 float* __restrict__ out) {
    __shared__ _Float16 Ps[2][128 * 72] __attribute__((aligned(16)));  // 36,864 B
    __shared__ float linv[128];
    int id = blockIdx.x;
    int b  = id & 7;            // XCD-local batch
    int j0 = (id >> 3) * 128;
    int t = threadIdx.x;
    int w = t >> 6, lane = t & 63, col = lane & 15, q = lane >> 4;
    int cb = (w & 3) * 64;      // wave's c-quarter for PV
    int jh = (w >> 2) * 64;     // wave's j-half for PV
    const _Float16* FGb = FG + (size_t)b * N_ * 64;
    const _Float16* Vb  = V + (size_t)b * C_ * N_;
    // Q frag (loop-invariant): wave w owns S columns j = j0 + w*16 .. +16
    half8 bq = *(const half8*)&FGb[(size_t)(j0 + w * 16 + col) * 64 + 32 + q * 8];
    floatx4 acc[4][4];
#pragma unroll
    for (int ct = 0; ct < 4; ++ct)
#pragma unroll
        for (int jt = 0; jt < 4; ++jt) acc[ct][jt] = (floatx4){0.f, 0.f, 0.f, 0.f};
    float lacc = 0.f;
    for (int it = 0; it < 64; ++it) {
        int i0 = it * 64;
        // V frags direct from global (issued early; consumed after the barrier)
        half8 afr[2][4];
#pragma unroll
        for (int kk = 0; kk < 2; ++kk)
#pragma unroll
            for (int ct = 0; ct < 4; ++ct)
                afr[kk][ct] = *(const half8*)&Vb[(size_t)(cb + ct * 16 + col) * N_ + i0 + kk * 32 + q * 8];
        // K frags direct from global
        half8 aK[4];
#pragma unroll
        for (int itile = 0; itile < 4; ++itile)
            aK[itile] = *(const half8*)&FGb[(size_t)(i0 + itile * 16 + col) * 64 + q * 8];
        _Float16* Pw = Ps[it & 1];
#pragma unroll
        for (int itile = 0; itile < 4; ++itile) {
            floatx4 s = __builtin_amdgcn_mfma_f32_16x16x32_f16(aK[itile], bq,
                                                               (floatx4){0.f, 0.f, 0.f, 0.f}, 0, 0, 0);
            half4 ph;
#pragma unroll
            for (int r = 0; r < 4; ++r) {
                float p = exp2f((s[r] - SHIFT) * LOG2E);
                lacc += p;
                ph[r] = (_Float16)p;
            }
            // P^T into LDS: row j_local = w*16+col, i-offset itile*16 + q*4
            *(half4*)&Pw[(w * 16 + col) * 72 + itile * 16 + q * 4] = ph;
        }
        __syncthreads();   // the ONLY barrier per iter (Ps double-buffered)
#pragma unroll
        for (int kk = 0; kk < 2; ++kk) {
            half8 bfr[4];
#pragma unroll
            for (int jt = 0; jt < 4; ++jt)
                bfr[jt] = *(const half8*)&Pw[(jh + jt * 16 + col) * 72 + kk * 32 + q * 8];
#pragma unroll
            for (int ct = 0; ct < 4; ++ct)
#pragma unroll
                for (int jt = 0; jt < 4; ++jt)
                    acc[ct][jt] = __builtin_amdgcn_mfma_f32_16x16x32_f16(afr[kk][ct], bfr[jt], acc[ct][jt], 0, 0, 0);
        }
    }
    // finalize l: lane holds partial for column j = w*16+col over its quad rows
    lacc += __shfl_xor(lacc, 16, 64);
    lacc += __shfl_xor(lacc, 32, 64);
    if (lane < 16) linv[w * 16 + lane] = 1.0f / lacc;
    __syncthreads();
    float gamma = gptr[0];
    const float* xb = x + ((size_t)(b * C_)) * N_;
    float* ob = out + ((size_t)(b * C_)) * N_;
#pragma unroll
    for (int jt = 0; jt < 4; ++jt) {
        float li = linv[jh + jt * 16 + col];
        int j = j0 + jh + jt * 16 + col;
#pragma unroll
        for (int ct = 0; ct < 4; ++ct)
#pragma unroll
            for (int r = 0; r < 4; ++r) {
                int c = cb + ct * 16 + q * 4 + r;
                size_t off = (size_t)c * N_ + j;
                ob[off] = gamma * acc[ct][jt][r] * li + xb[off];
            }
    }
}

extern "C" void kernel_launch(void* const* d_in, const int* in_sizes, int n_in,
                              void* d_out, int out_size, void* d_ws, size_t ws_size,
                              hipStream_t stream) {
    const float* x  = (const float*)d_in[0];
    const float* wq = (const float*)d_in[1];
    const float* bq = (const float*)d_in[2];
    const float* wk = (const float*)d_in[3];
    const float* bk = (const float*)d_in[4];
    const float* wv = (const float*)d_in[5];
    const float* bv = (const float*)d_in[6];
    const float* gm = (const float*)d_in[7];
    float* out = (float*)d_out;
    char* ws = (char*)d_ws;
    _Float16* xT = (_Float16*)ws;                     // 16,777,216 B  [B][N][C]
    _Float16* FG = (_Float16*)(ws + 16777216);        //  4,194,304 B  [B][N][64] (f|g)
    _Float16* V  = (_Float16*)(ws + 20971520);        // 16,777,216 B  [B][C][N]
    _Float16* Wh = (_Float16*)(ws + 37748736);        //    163,840 B  [320][256]
    float*    Bh = (float*)(ws + 37912576);           //      1,280 B

    k_transpose<<<dim3(64, 4, 8), 256, 0, stream>>>(x, xT);
    k_wprep<<<dim3(320), 256, 0, stream>>>(wq, bq, wk, bk, wv, bv, Wh, Bh);
    k_proj<<<dim3(512), 256, 0, stream>>>(xT, Wh, Bh, FG, V);
    k_attn<<<dim3(256), 512, 0, stream>>>(FG, V, x, gm, out);
}

// Round 3
// 239.132 us; speedup vs baseline: 1.4585x; 1.4585x over previous
//
#include <hip/hip_runtime.h>
#include <stdint.h>

#define B_ 8
#define C_ 256
#define N_ 4096
#define LOG2E 1.44269504088896f
#define SHIFT 14.0f

typedef _Float16 half8 __attribute__((ext_vector_type(8)));
typedef _Float16 half4 __attribute__((ext_vector_type(4)));
typedef float floatx4 __attribute__((ext_vector_type(4)));

// ---------------- K0: weight concat + fp16 cast: Wh[320][256], Bh[320] ------
// rows 0..31 = wq (-> K/f), 32..63 = wk (-> Q/g), 64..319 = wv (-> V)
__global__ __launch_bounds__(256) void k_wprep(const float* __restrict__ wq, const float* __restrict__ bq,
                                               const float* __restrict__ wk, const float* __restrict__ bk,
                                               const float* __restrict__ wv, const float* __restrict__ bv,
                                               _Float16* __restrict__ Wh, float* __restrict__ Bh) {
    int r = blockIdx.x;   // 0..319
    int t = threadIdx.x;  // 0..255
    const float* src;
    float bias;
    if (r < 32)      { src = wq + r * 256;        bias = bq[r]; }
    else if (r < 64) { src = wk + (r - 32) * 256; bias = bk[r - 32]; }
    else             { src = wv + (r - 64) * 256; bias = bv[r - 64]; }
    Wh[r * 256 + t] = (_Float16)src[t];
    if (t == 0) Bh[r] = bias;
}

// ---------------- K1: fused transpose + projection GEMM ---------------------
// D[i][n] = sum_c x[b][c][i] * Wh[n][c] + Bh[n]
// Outputs in MFMA-fragment-friendly layouts:
//   Kf[b][i>>5][k>>3][i&31][k&7]  (k = n in 0..32)        2 MB
//   Qf[b][j>>5][k>>3][j&31][k&7]  (k = n-32)              2 MB
//   Vf[b][i>>4][c][i&15]          (c = n-64)             16.8 MB
__global__ __launch_bounds__(256, 2) void k_proj(const float* __restrict__ x,
                                                 const _Float16* __restrict__ Wh,
                                                 const float* __restrict__ Bh,
                                                 _Float16* __restrict__ Kf,
                                                 _Float16* __restrict__ Qf,
                                                 _Float16* __restrict__ Vf) {
    __shared__ _Float16 As[64 * 264] __attribute__((aligned(16)));  // [i][c], stride 264
    __shared__ _Float16 Bs[320 * 40] __attribute__((aligned(16)));
    int id = blockIdx.x;
    int b  = id & 7;          // XCD-local batch
    int i0 = (id >> 3) * 64;
    int t = threadIdx.x;
    int w = t >> 6, lane = t & 63, col = lane & 15, q = lane >> 4;
    // ---- stage x-tile transposed+cast: As[i][c] = (fp16)x[b][c][i0+i]
    {
        int rowg = t & 63;    // c-group: c = rowg*4 + rr
        int colg = t >> 6;    // i-chunk: i = colg*16 + jj
        const float* xb = x + (size_t)b * C_ * N_ + i0;
        float4 xv[4][4];
#pragma unroll
        for (int rr = 0; rr < 4; ++rr)
#pragma unroll
            for (int p = 0; p < 4; ++p)
                xv[rr][p] = *(const float4*)&xb[(size_t)(rowg * 4 + rr) * N_ + colg * 16 + p * 4];
#pragma unroll
        for (int jj = 0; jj < 16; ++jj) {
            half4 h;
#pragma unroll
            for (int rr = 0; rr < 4; ++rr) h[rr] = (_Float16)xv[rr][jj >> 2][jj & 3];
            *(half4*)&As[(colg * 16 + jj) * 264 + rowg * 4] = h;  // bank = 2*lane -> free
        }
    }
    floatx4 acc[4][5];
#pragma unroll
    for (int mt = 0; mt < 4; ++mt)
#pragma unroll
        for (int nt = 0; nt < 5; ++nt) acc[mt][nt] = (floatx4){0.f, 0.f, 0.f, 0.f};
    for (int kc = 0; kc < 8; ++kc) {
        int k0 = kc * 32;
#pragma unroll
        for (int rep = 0; rep < 5; ++rep) {  // stage B tile: 320 rows x 32 k
            int idx = t + rep * 256;
            int row = idx >> 2, part = idx & 3;
            *(uint4*)&Bs[row * 40 + part * 8] = *(const uint4*)&Wh[row * 256 + k0 + part * 8];
        }
        __syncthreads();
        half8 a[4], bf[5];
#pragma unroll
        for (int mt = 0; mt < 4; ++mt) a[mt] = *(const half8*)&As[(mt * 16 + col) * 264 + k0 + q * 8];
#pragma unroll
        for (int nt = 0; nt < 5; ++nt) bf[nt] = *(const half8*)&Bs[(w * 80 + nt * 16 + col) * 40 + q * 8];
#pragma unroll
        for (int mt = 0; mt < 4; ++mt)
#pragma unroll
            for (int nt = 0; nt < 5; ++nt)
                acc[mt][nt] = __builtin_amdgcn_mfma_f32_16x16x32_f16(a[mt], bf[nt], acc[mt][nt], 0, 0, 0);
        __syncthreads();
    }
    // epilogue: bias + scatter into fragment layouts (branch uniform per (w,nt))
#pragma unroll
    for (int nt = 0; nt < 5; ++nt) {
        int n = w * 80 + nt * 16 + col;
        float bias = Bh[n];
        if (n < 32) {
#pragma unroll
            for (int mt = 0; mt < 4; ++mt)
#pragma unroll
                for (int r = 0; r < 4; ++r) {
                    int i = i0 + mt * 16 + q * 4 + r;
                    Kf[((((size_t)b * 128 + (i >> 5)) * 4 + (n >> 3)) * 32 + (i & 31)) * 8 + (n & 7)]
                        = (_Float16)(acc[mt][nt][r] + bias);
                }
        } else if (n < 64) {
            int n2 = n - 32;
#pragma unroll
            for (int mt = 0; mt < 4; ++mt)
#pragma unroll
                for (int r = 0; r < 4; ++r) {
                    int j = i0 + mt * 16 + q * 4 + r;
                    Qf[((((size_t)b * 128 + (j >> 5)) * 4 + (n2 >> 3)) * 32 + (j & 31)) * 8 + (n2 & 7)]
                        = (_Float16)(acc[mt][nt][r] + bias);
                }
        } else {
            int c = n - 64;
#pragma unroll
            for (int mt = 0; mt < 4; ++mt) {
                int ib = (i0 >> 4) + mt;  // i&15 = q*4+r
                half4 v4;
#pragma unroll
                for (int r = 0; r < 4; ++r) v4[r] = (_Float16)(acc[mt][nt][r] + bias);
                *(half4*)&Vf[(((size_t)b * 256 + ib) * 256 + c) * 16 + q * 4] = v4;
            }
        }
    }
}

// ---------------- K2: fused attention v3 ------------------------------------
// 512 thr (8 waves), j-tile 128, grid 256 (1 block/CU), b = id&7 XCD-pinned.
// S: wave w owns j-strip w*16 (Q frag in regs, K tile via global_load_lds DMA,
//    double-buffered). P^T through LDS (single buffer, 2 barriers/iter).
// PV: wave (cq=w&3, jh=w>>2) owns 64c x 64j; V A-frags register-double-buffered
//    direct from L2-resident Vf (contiguous 1KB/wave-load), prefetched one
//    iteration ahead so the barrier's vmcnt(0) drain finds them ~complete.
#define ATTN_STEP(IT, VCUR, VNXT, KCUR, KNXT)                                              \
    {                                                                                      \
        _Pragma("unroll")                                                                  \
        for (int itile = 0; itile < 4; ++itile) {                                          \
            half8 aK = *(const half8*)&KCUR[(((itile >> 1) * 4 + q) * 32 +                 \
                                             (itile & 1) * 16 + col) * 8];                 \
            floatx4 s = __builtin_amdgcn_mfma_f32_16x16x32_f16(                            \
                aK, bq, (floatx4){0.f, 0.f, 0.f, 0.f}, 0, 0, 0);                           \
            half4 ph;                                                                      \
            _Pragma("unroll")                                                              \
            for (int r = 0; r < 4; ++r) {                                                  \
                float p = exp2f((s[r] - SHIFT) * LOG2E);                                   \
                lacc += p;                                                                 \
                ph[r] = (_Float16)p;                                                       \
            }                                                                              \
            *(half4*)&Ps[(w * 16 + col) * 72 + itile * 16 + q * 4] = ph;                   \
        }                                                                                  \
        __syncthreads(); /* barrier1: P visible; prior K-DMA drained last iter */          \
        if ((IT) < 63) {                                                                   \
            if (w < 4)                                                                     \
                __builtin_amdgcn_global_load_lds(                                          \
                    (const __attribute__((address_space(1))) uint32_t*)(Kfb +              \
                        ((IT) + 1) * 2048 + w * 512 + lane * 8),                           \
                    (__attribute__((address_space(3))) uint32_t*)&KNXT[w * 512],           \
                    16, 0, 0);                                                             \
            _Pragma("unroll")                                                              \
            for (int ct = 0; ct < 4; ++ct)                                                 \
                _Pragma("unroll")                                                          \
                for (int kk = 0; kk < 2; ++kk)                                             \
                    VNXT[ct * 2 + kk] = *(const half8*)&Vfb[                               \
                        ((size_t)(((IT) + 1) * 4 + kk * 2 + (q >> 1)) * 256 +              \
                         cq * 64 + ct * 16 + col) * 16 + (q & 1) * 8];                     \
        }                                                                                  \
        _Pragma("unroll")                                                                  \
        for (int kk = 0; kk < 2; ++kk) {                                                   \
            half8 bfr[4];                                                                  \
            _Pragma("unroll")                                                              \
            for (int jt = 0; jt < 4; ++jt)                                                 \
                bfr[jt] = *(const half8*)&Ps[(jh * 64 + jt * 16 + col) * 72 +              \
                                             kk * 32 + q * 8];                             \
            _Pragma("unroll")                                                              \
            for (int ct = 0; ct < 4; ++ct)                                                 \
                _Pragma("unroll")                                                          \
                for (int jt = 0; jt < 4; ++jt)                                             \
                    acc[ct][jt] = __builtin_amdgcn_mfma_f32_16x16x32_f16(                  \
                        VCUR[ct * 2 + kk], bfr[jt], acc[ct][jt], 0, 0, 0);                 \
        }                                                                                  \
        __syncthreads(); /* barrier2: Ps WAR; drains K-DMA + V prefetch (in flight ~PV) */ \
    }

__global__ __launch_bounds__(512, 2) void k_attn(const _Float16* __restrict__ Kf,
                                                 const _Float16* __restrict__ Qf,
                                                 const _Float16* __restrict__ Vf,
                                                 const float* __restrict__ x,
                                                 const float* __restrict__ gptr,
                                                 float* __restrict__ out) {
    __shared__ _Float16 Ks[2][2048] __attribute__((aligned(16)));  //  8,192 B (flat Kf-tile copies)
    __shared__ _Float16 Ps[128 * 72] __attribute__((aligned(16))); // 18,432 B
    __shared__ float linv[128];
    int id = blockIdx.x;
    int b  = id & 7;            // XCD-local batch
    int j0 = (id >> 3) * 128;
    int t = threadIdx.x;
    int w = t >> 6, lane = t & 63, col = lane & 15, q = lane >> 4;
    int cq = w & 3, jh = w >> 2;
    const _Float16* Kfb = Kf + (size_t)b * 131072;
    const _Float16* Qfb = Qf + (size_t)b * 131072;
    const _Float16* Vfb = Vf + (size_t)b * 1048576;
    // Q frag (loop-invariant): wave w owns S columns j = j0 + w*16 .. +16
    half8 bq = *(const half8*)&Qfb[((((j0 >> 5) + (w >> 1)) * 4 + q) * 32 + (w & 1) * 16 + col) * 8];
    floatx4 acc[4][4];
#pragma unroll
    for (int ct = 0; ct < 4; ++ct)
#pragma unroll
        for (int jt = 0; jt < 4; ++jt) acc[ct][jt] = (floatx4){0.f, 0.f, 0.f, 0.f};
    float lacc = 0.f;
    // prologue: K-DMA for it=0, V prefetch for it=0 into vA
    if (w < 4)
        __builtin_amdgcn_global_load_lds(
            (const __attribute__((address_space(1))) uint32_t*)(Kfb + w * 512 + lane * 8),
            (__attribute__((address_space(3))) uint32_t*)&Ks[0][w * 512], 16, 0, 0);
    half8 vA[8], vB[8];
#pragma unroll
    for (int ct = 0; ct < 4; ++ct)
#pragma unroll
        for (int kk = 0; kk < 2; ++kk)
            vA[ct * 2 + kk] = *(const half8*)&Vfb[
                ((size_t)(kk * 2 + (q >> 1)) * 256 + cq * 64 + ct * 16 + col) * 16 + (q & 1) * 8];
    __syncthreads();
    for (int it2 = 0; it2 < 32; ++it2) {
        int it = it2 * 2;
        ATTN_STEP(it,     vA, vB, (&Ks[0][0]), (&Ks[1][0]))
        ATTN_STEP(it + 1, vB, vA, (&Ks[1][0]), (&Ks[0][0]))
    }
    // l finalize: each wave covered ALL i for its j-strip; reduce over quads
    lacc += __shfl_xor(lacc, 16, 64);
    lacc += __shfl_xor(lacc, 32, 64);
    if (lane < 16) linv[w * 16 + lane] = 1.0f / lacc;
    __syncthreads();
    float gamma = gptr[0];
    const float* xb = x + (size_t)b * C_ * N_;
    float* ob = out + (size_t)b * C_ * N_;
#pragma unroll
    for (int jt = 0; jt < 4; ++jt) {
        int jl = jh * 64 + jt * 16 + col;
        float li = linv[jl];
        int j = j0 + jl;
#pragma unroll
        for (int ct = 0; ct < 4; ++ct)
#pragma unroll
            for (int r = 0; r < 4; ++r) {
                int c = cq * 64 + ct * 16 + q * 4 + r;
                size_t off = (size_t)c * N_ + j;
                ob[off] = gamma * acc[ct][jt][r] * li + xb[off];
            }
    }
}

extern "C" void kernel_launch(void* const* d_in, const int* in_sizes, int n_in,
                              void* d_out, int out_size, void* d_ws, size_t ws_size,
                              hipStream_t stream) {
    const float* x  = (const float*)d_in[0];
    const float* wq = (const float*)d_in[1];
    const float* bq = (const float*)d_in[2];
    const float* wk = (const float*)d_in[3];
    const float* bk = (const float*)d_in[4];
    const float* wv = (const float*)d_in[5];
    const float* bv = (const float*)d_in[6];
    const float* gm = (const float*)d_in[7];
    float* out = (float*)d_out;
    char* ws = (char*)d_ws;
    // workspace layout (~21.1 MB)
    _Float16* Vf = (_Float16*)ws;                     // 16,777,216 B
    _Float16* Kf = (_Float16*)(ws + 16777216);        //  2,097,152 B
    _Float16* Qf = (_Float16*)(ws + 18874368);        //  2,097,152 B
    _Float16* Wh = (_Float16*)(ws + 20971520);        //    163,840 B
    float*    Bh = (float*)(ws + 21135360);           //      1,280 B

    k_wprep<<<dim3(320), 256, 0, stream>>>(wq, bq, wk, bk, wv, bv, Wh, Bh);
    k_proj<<<dim3(512), 256, 0, stream>>>(x, Wh, Bh, Kf, Qf, Vf);
    k_attn<<<dim3(256), 512, 0, stream>>>(Kf, Qf, Vf, x, gm, out);
}

// Round 4
// 205.797 us; speedup vs baseline: 1.6947x; 1.1620x over previous
//
#include <hip/hip_runtime.h>
#include <stdint.h>

#define B_ 8
#define C_ 256
#define N_ 4096
#define LOG2E 1.44269504088896f
#define SHIFT 14.0f

typedef _Float16 half8 __attribute__((ext_vector_type(8)));
typedef _Float16 half4 __attribute__((ext_vector_type(4)));
typedef float floatx4 __attribute__((ext_vector_type(4)));

// ---------------- K0a: transpose-cast x[b][c][i] fp32 -> xT[b][i][c] fp16 ----
__global__ __launch_bounds__(256) void k_transpose(const float* __restrict__ x,
                                                   _Float16* __restrict__ xT) {
    __shared__ float tile[64][65];
    int i0 = blockIdx.x * 64;
    int c0 = blockIdx.y * 64;
    int b  = blockIdx.z;
    int t  = threadIdx.x;
    const float* xb = x + ((size_t)(b * C_ + c0)) * N_ + i0;
    int r4 = t >> 4;            // 0..15
    int c4 = (t & 15) * 4;      // i-offset 0..60
#pragma unroll
    for (int k = 0; k < 4; ++k) {
        int r = k * 16 + r4;    // c-row 0..63
        *(float4*)&tile[r][c4] = *(const float4*)&xb[(size_t)r * N_ + c4];
    }
    __syncthreads();
    _Float16* xTb = xT + ((size_t)(b * N_ + i0)) * C_ + c0;
    int i2 = t >> 2;            // i-row 0..63
#pragma unroll
    for (int g = 0; g < 2; ++g) {
        int ch = (t & 3) + g * 4;   // c-chunk 0..7 (8 halves each)
        half8 v;
#pragma unroll
        for (int j = 0; j < 8; ++j) v[j] = (_Float16)tile[ch * 8 + j][i2];
        *(half8*)&xTb[(size_t)i2 * C_ + ch * 8] = v;
    }
}

// ---------------- K0b: weights -> fragment-ordered fp16 Whf + Bh ------------
// n: 0..31 = wq (-> K/f), 32..63 = wk (-> Q/g), 64..319 = wv (-> V)
// Whf[(k>>3)][n][k&7]  (slot-major so a B-frag load is 16B contiguous/lane)
__global__ __launch_bounds__(256) void k_wprep(const float* __restrict__ wq, const float* __restrict__ bq,
                                               const float* __restrict__ wk, const float* __restrict__ bk,
                                               const float* __restrict__ wv, const float* __restrict__ bv,
                                               _Float16* __restrict__ Whf, float* __restrict__ Bh) {
    int r = blockIdx.x;   // n: 0..319
    int t = threadIdx.x;  // k: 0..255
    const float* src;
    float bias;
    if (r < 32)      { src = wq + r * 256;        bias = bq[r]; }
    else if (r < 64) { src = wk + (r - 32) * 256; bias = bk[r - 32]; }
    else             { src = wv + (r - 64) * 256; bias = bv[r - 64]; }
    Whf[(t >> 3) * 2560 + r * 8 + (t & 7)] = (_Float16)src[t];
    if (t == 0) Bh[r] = bias;
}

// ---------------- K1: projection GEMM (xT coalesced, no Bs, no loop barriers)
// D[i][n] = sum_c xT[i][c] * Wh[n][c] + Bh[n]
// Outputs (MFMA-fragment layouts):
//   Kf[b][i>>5][k>>3][i&31][k&7]  (k = n)          2 MB
//   Qf[b][j>>5][k>>3][j&31][k&7]  (k = n-32)       2 MB
//   Vf[b][i>>4][c][i&15]          (c = n-64)      16.8 MB
__global__ __launch_bounds__(256) void k_proj(const _Float16* __restrict__ xT,
                                              const _Float16* __restrict__ Whf,
                                              const float* __restrict__ Bh,
                                              _Float16* __restrict__ Kf,
                                              _Float16* __restrict__ Qf,
                                              _Float16* __restrict__ Vf) {
    __shared__ _Float16 As[64 * 264] __attribute__((aligned(16)));  // 33,792 B
    int id = blockIdx.x;
    int b  = id & 7;          // XCD-local batch
    int i0 = (id >> 3) * 64;
    int t = threadIdx.x;
    int w = t >> 6, lane = t & 63, col = lane & 15, q = lane >> 4;
    const _Float16* xTb = xT + ((size_t)(b * N_ + i0)) * 256;
#pragma unroll
    for (int rep = 0; rep < 8; ++rep) {   // stage A tile 64i x 256k, coalesced
        int idx = t + rep * 256;
        int i = idx >> 5, part = idx & 31;
        *(uint4*)&As[i * 264 + part * 8] = *(const uint4*)&xTb[(size_t)i * 256 + part * 8];
    }
    __syncthreads();
    floatx4 acc[4][5];
#pragma unroll
    for (int mt = 0; mt < 4; ++mt)
#pragma unroll
        for (int nt = 0; nt < 5; ++nt) acc[mt][nt] = (floatx4){0.f, 0.f, 0.f, 0.f};
    for (int kc = 0; kc < 8; ++kc) {
        half8 a[4], bf[5];
#pragma unroll
        for (int nt = 0; nt < 5; ++nt)
            bf[nt] = *(const half8*)&Whf[(kc * 4 + q) * 2560 + (w * 80 + nt * 16 + col) * 8];
#pragma unroll
        for (int mt = 0; mt < 4; ++mt)
            a[mt] = *(const half8*)&As[(mt * 16 + col) * 264 + kc * 32 + q * 8];
#pragma unroll
        for (int mt = 0; mt < 4; ++mt)
#pragma unroll
            for (int nt = 0; nt < 5; ++nt)
                acc[mt][nt] = __builtin_amdgcn_mfma_f32_16x16x32_f16(a[mt], bf[nt], acc[mt][nt], 0, 0, 0);
    }
    // epilogue: bias + scatter into fragment layouts (branch uniform per (w,nt))
#pragma unroll
    for (int nt = 0; nt < 5; ++nt) {
        int n = w * 80 + nt * 16 + col;
        float bias = Bh[n];
        if (n < 32) {
#pragma unroll
            for (int mt = 0; mt < 4; ++mt)
#pragma unroll
                for (int r = 0; r < 4; ++r) {
                    int i = i0 + mt * 16 + q * 4 + r;
                    Kf[((((size_t)b * 128 + (i >> 5)) * 4 + (n >> 3)) * 32 + (i & 31)) * 8 + (n & 7)]
                        = (_Float16)(acc[mt][nt][r] + bias);
                }
        } else if (n < 64) {
            int n2 = n - 32;
#pragma unroll
            for (int mt = 0; mt < 4; ++mt)
#pragma unroll
                for (int r = 0; r < 4; ++r) {
                    int j = i0 + mt * 16 + q * 4 + r;
                    Qf[((((size_t)b * 128 + (j >> 5)) * 4 + (n2 >> 3)) * 32 + (j & 31)) * 8 + (n2 & 7)]
                        = (_Float16)(acc[mt][nt][r] + bias);
                }
        } else {
            int c = n - 64;
#pragma unroll
            for (int mt = 0; mt < 4; ++mt) {
                int ib = (i0 >> 4) + mt;  // i&15 = q*4+r
                half4 v4;
#pragma unroll
                for (int r = 0; r < 4; ++r) v4[r] = (_Float16)(acc[mt][nt][r] + bias);
                *(half4*)&Vf[(((size_t)b * 256 + ib) * 256 + c) * 16 + q * 4] = v4;
            }
        }
    }
}

// ---------------- K2: fused attention v4 ------------------------------------
// 512 thr (8 waves), j-tile 64, grid 512 = 2 blocks/CU (16 waves/CU).
// S roles:  wave w -> j-strip jts=w&3, i-half ihs=w>>2 (2 MFMA/iter).
// PV roles: wave w -> c-strip w*32, ALL 64 j (W_j=1: V read once from L2,
//           which is XCD-resident: batch b's 2MB Vf lives in XCD b's L2).
// One barrier per iter: PV(it) reads Ps[it&1] while S(it+1) writes Ps[~it&1].
__global__ __launch_bounds__(512, 4) void k_attn(const _Float16* __restrict__ Kf,
                                                 const _Float16* __restrict__ Qf,
                                                 const _Float16* __restrict__ Vf,
                                                 const float* __restrict__ x,
                                                 const float* __restrict__ gptr,
                                                 float* __restrict__ out) {
    __shared__ _Float16 Ps[2][64 * 72] __attribute__((aligned(16)));  // 18,432 B
    __shared__ float Lp[2][64];
    int id = blockIdx.x;
    int b  = id & 7;            // XCD-local batch
    int j0 = (id >> 3) * 64;    // 64 j-blocks
    int t = threadIdx.x;
    int w = t >> 6, lane = t & 63, col = lane & 15, q = lane >> 4;
    int jts = w & 3, ihs = w >> 2;   // S role
    int cw  = w * 32;                // PV c-strip
    const _Float16* Kfb = Kf + (size_t)b * 131072;
    const _Float16* Qfb = Qf + (size_t)b * 131072;
    const _Float16* Vfb = Vf + (size_t)b * 1048576;
    // Q frag (loop-invariant) for j = j0 + jts*16 + col
    int jj = j0 + jts * 16;
    half8 bq = *(const half8*)&Qfb[((((jj >> 5)) * 4 + q) * 32 + ((jj & 31) + col)) * 8];
    floatx4 acc[2][4];
#pragma unroll
    for (int ct = 0; ct < 2; ++ct)
#pragma unroll
        for (int jt = 0; jt < 4; ++jt) acc[ct][jt] = (floatx4){0.f, 0.f, 0.f, 0.f};
    float lacc = 0.f;
    // ---- prologue: S_0 into Ps[0]
    {
        half8 aK0[2];
#pragma unroll
        for (int itl = 0; itl < 2; ++itl)
            aK0[itl] = *(const half8*)&Kfb[((((size_t)0 * 2 + ihs) * 4 + q) * 32 + itl * 16 + col) * 8];
#pragma unroll
        for (int itl = 0; itl < 2; ++itl) {
            floatx4 s = __builtin_amdgcn_mfma_f32_16x16x32_f16(aK0[itl], bq,
                                                               (floatx4){0.f, 0.f, 0.f, 0.f}, 0, 0, 0);
            half4 ph;
#pragma unroll
            for (int r = 0; r < 4; ++r) {
                float p = exp2f((s[r] - SHIFT) * LOG2E);
                lacc += p;
                ph[r] = (_Float16)p;
            }
            *(half4*)&Ps[0][(jts * 16 + col) * 72 + ihs * 32 + itl * 16 + q * 4] = ph;
        }
    }
    __syncthreads();
    // ---- main loop: one barrier per iteration
    for (int it = 0; it < 64; ++it) {
        const _Float16* cur = Ps[it & 1];
        _Float16* nxt = Ps[(it + 1) & 1];
        // V frags for PV(it): contiguous 1KB/wave-instr, L2-resident
        half8 vA[4];
#pragma unroll
        for (int kk = 0; kk < 2; ++kk)
#pragma unroll
            for (int ct = 0; ct < 2; ++ct)
                vA[ct * 2 + kk] = *(const half8*)&Vfb[
                    (((size_t)(it * 4 + kk * 2 + (q >> 1))) * 256 + cw + ct * 16 + col) * 16 + (q & 1) * 8];
        // K frags for S(it+1)
        half8 aKr[2];
        if (it < 63) {
#pragma unroll
            for (int itl = 0; itl < 2; ++itl)
                aKr[itl] = *(const half8*)&Kfb[((((it + 1) * 2 + ihs) * 4 + q) * 32 + itl * 16 + col) * 8];
        }
        // PV(it): O += V * P
#pragma unroll
        for (int kk = 0; kk < 2; ++kk) {
            half8 bfr[4];
#pragma unroll
            for (int jt = 0; jt < 4; ++jt)
                bfr[jt] = *(const half8*)&cur[(jt * 16 + col) * 72 + kk * 32 + q * 8];
#pragma unroll
            for (int ct = 0; ct < 2; ++ct)
#pragma unroll
                for (int jt = 0; jt < 4; ++jt)
                    acc[ct][jt] = __builtin_amdgcn_mfma_f32_16x16x32_f16(vA[ct * 2 + kk], bfr[jt], acc[ct][jt], 0, 0, 0);
        }
        // S(it+1) -> nxt
        if (it < 63) {
#pragma unroll
            for (int itl = 0; itl < 2; ++itl) {
                floatx4 s = __builtin_amdgcn_mfma_f32_16x16x32_f16(aKr[itl], bq,
                                                                   (floatx4){0.f, 0.f, 0.f, 0.f}, 0, 0, 0);
                half4 ph;
#pragma unroll
                for (int r = 0; r < 4; ++r) {
                    float p = exp2f((s[r] - SHIFT) * LOG2E);
                    lacc += p;
                    ph[r] = (_Float16)p;
                }
                *(half4*)&nxt[(jts * 16 + col) * 72 + ihs * 32 + itl * 16 + q * 4] = ph;
            }
        }
        __syncthreads();
    }
    // ---- l finalize: reduce quads; waves (jts,ihs) cover all 128 slots of Lp
    lacc += __shfl_xor(lacc, 16, 64);
    lacc += __shfl_xor(lacc, 32, 64);
    if (lane < 16) Lp[ihs][jts * 16 + lane] = lacc;
    __syncthreads();
    float gamma = gptr[0];
    const float* xb = x + (size_t)b * C_ * N_;
    float* ob = out + (size_t)b * C_ * N_;
#pragma unroll
    for (int jt = 0; jt < 4; ++jt) {
        int jl = jt * 16 + col;
        float li = 1.0f / (Lp[0][jl] + Lp[1][jl]);
        int j = j0 + jl;
#pragma unroll
        for (int ct = 0; ct < 2; ++ct)
#pragma unroll
            for (int r = 0; r < 4; ++r) {
                int c = cw + ct * 16 + q * 4 + r;
                size_t off = (size_t)c * N_ + j;
                ob[off] = gamma * acc[ct][jt][r] * li + xb[off];
            }
    }
}

extern "C" void kernel_launch(void* const* d_in, const int* in_sizes, int n_in,
                              void* d_out, int out_size, void* d_ws, size_t ws_size,
                              hipStream_t stream) {
    const float* x  = (const float*)d_in[0];
    const float* wq = (const float*)d_in[1];
    const float* bq = (const float*)d_in[2];
    const float* wk = (const float*)d_in[3];
    const float* bk = (const float*)d_in[4];
    const float* wv = (const float*)d_in[5];
    const float* bv = (const float*)d_in[6];
    const float* gm = (const float*)d_in[7];
    float* out = (float*)d_out;
    char* ws = (char*)d_ws;
    // workspace layout (~37.9 MB)
    _Float16* xT  = (_Float16*)ws;                    // 16,777,216 B  [B][N][C]
    _Float16* Vf  = (_Float16*)(ws + 16777216);       // 16,777,216 B
    _Float16* Kf  = (_Float16*)(ws + 33554432);       //  2,097,152 B
    _Float16* Qf  = (_Float16*)(ws + 35651584);       //  2,097,152 B
    _Float16* Whf = (_Float16*)(ws + 37748736);       //    163,840 B
    float*    Bh  = (float*)(ws + 37912576);          //      1,280 B

    k_transpose<<<dim3(64, 4, 8), 256, 0, stream>>>(x, xT);
    k_wprep<<<dim3(320), 256, 0, stream>>>(wq, bq, wk, bk, wv, bv, Whf, Bh);
    k_proj<<<dim3(512), 256, 0, stream>>>(xT, Whf, Bh, Kf, Qf, Vf);
    k_attn<<<dim3(512), 512, 0, stream>>>(Kf, Qf, Vf, x, gm, out);
}

// Round 6
// 188.486 us; speedup vs baseline: 1.8504x; 1.0918x over previous
//
#include <hip/hip_runtime.h>
#include <stdint.h>

#define B_ 8
#define C_ 256
#define N_ 4096
#define LOG2E 1.44269504088896f
#define NSHIFT_L2E (-14.0f * 1.44269504088896f)   // exp(s-14) = exp2(s*log2e - 14*log2e)

typedef _Float16 half8 __attribute__((ext_vector_type(8)));
typedef _Float16 half4 __attribute__((ext_vector_type(4)));
typedef float floatx4 __attribute__((ext_vector_type(4)));

// ---------------- K0: weights -> fragment-ordered fp16 Whf + Bh -------------
// n: 0..31 = wq (-> K/f), 32..63 = wk (-> Q/g), 64..319 = wv (-> V)
// Whf[(k>>3)][n][k&7]  (16B contiguous per B-frag lane)
__global__ __launch_bounds__(256) void k_wprep(const float* __restrict__ wq, const float* __restrict__ bq,
                                               const float* __restrict__ wk, const float* __restrict__ bk,
                                               const float* __restrict__ wv, const float* __restrict__ bv,
                                               _Float16* __restrict__ Whf, float* __restrict__ Bh) {
    int r = blockIdx.x;   // n: 0..319
    int t = threadIdx.x;  // k: 0..255
    const float* src;
    float bias;
    if (r < 32)      { src = wq + r * 256;        bias = bq[r]; }
    else if (r < 64) { src = wk + (r - 32) * 256; bias = bk[r - 32]; }
    else             { src = wv + (r - 64) * 256; bias = bv[r - 64]; }
    Whf[(t >> 3) * 2560 + r * 8 + (t & 7)] = (_Float16)src[t];
    if (t == 0) Bh[r] = bias;
}

// ---------------- K1: fused transpose + projection GEMM ---------------------
// Reads x[b][c][i] directly (coalesced along i), transposes via LDS chunks,
// then GEMM from As with global Whf B-frags (no in-GEMM barriers).
// Outputs (MFMA-fragment layouts):
//   Kf[b][i>>5][k>>3][i&31][k&7]  (k = n)          2 MB
//   Qf[b][j>>5][k>>3][j&31][k&7]  (k = n-32)       2 MB
//   Vf[b][i>>4][c][i&15]          (c = n-64)      16.8 MB
__global__ __launch_bounds__(256) void k_proj(const float* __restrict__ x,
                                              const _Float16* __restrict__ Whf,
                                              const float* __restrict__ Bh,
                                              _Float16* __restrict__ Kf,
                                              _Float16* __restrict__ Qf,
                                              _Float16* __restrict__ Vf) {
    __shared__ float xtile[64 * 65];                                 // 16,640 B
    __shared__ _Float16 As[64 * 264] __attribute__((aligned(16)));   // 33,792 B
    int id = blockIdx.x;
    int b  = id & 7;          // XCD-local batch
    int i0 = (id >> 3) * 64;
    int t = threadIdx.x;
    int w = t >> 6, lane = t & 63, col = lane & 15, q = lane >> 4;
    const float* xb = x + (size_t)b * C_ * N_ + i0;
    // ---- stage + transpose x in 4 chunks of 64 c
    for (int cc = 0; cc < 4; ++cc) {
        int cr = t >> 4;            // 0..15
        int ip = (t & 15) * 4;      // i-offset
#pragma unroll
        for (int k = 0; k < 4; ++k)
            *(float4*)&xtile[(cr + 16 * k) * 65 + ip] =
                *(const float4*)&xb[(size_t)(cc * 64 + cr + 16 * k) * N_ + ip];
        __syncthreads();
        int i = t & 63, cb2 = (t >> 6) * 16;
        float v[16];
#pragma unroll
        for (int k = 0; k < 16; ++k) v[k] = xtile[(cb2 + k) * 65 + i];  // bank = c+i: free
        half8 h0, h1;
#pragma unroll
        for (int k = 0; k < 8; ++k) { h0[k] = (_Float16)v[k]; h1[k] = (_Float16)v[8 + k]; }
        *(half8*)&As[i * 264 + cc * 64 + cb2] = h0;
        *(half8*)&As[i * 264 + cc * 64 + cb2 + 8] = h1;
        __syncthreads();
    }
    // ---- GEMM: no barriers, B-frags from L2-hot Whf
    floatx4 acc[4][5];
#pragma unroll
    for (int mt = 0; mt < 4; ++mt)
#pragma unroll
        for (int nt = 0; nt < 5; ++nt) acc[mt][nt] = (floatx4){0.f, 0.f, 0.f, 0.f};
    for (int kc = 0; kc < 8; ++kc) {
        half8 a[4], bf[5];
#pragma unroll
        for (int nt = 0; nt < 5; ++nt)
            bf[nt] = *(const half8*)&Whf[(kc * 4 + q) * 2560 + (w * 80 + nt * 16 + col) * 8];
#pragma unroll
        for (int mt = 0; mt < 4; ++mt)
            a[mt] = *(const half8*)&As[(mt * 16 + col) * 264 + kc * 32 + q * 8];
#pragma unroll
        for (int mt = 0; mt < 4; ++mt)
#pragma unroll
            for (int nt = 0; nt < 5; ++nt)
                acc[mt][nt] = __builtin_amdgcn_mfma_f32_16x16x32_f16(a[mt], bf[nt], acc[mt][nt], 0, 0, 0);
    }
    // ---- epilogue: bias + scatter (branch uniform per (w,nt))
#pragma unroll
    for (int nt = 0; nt < 5; ++nt) {
        int n = w * 80 + nt * 16 + col;
        float bias = Bh[n];
        if (n < 32) {
#pragma unroll
            for (int mt = 0; mt < 4; ++mt)
#pragma unroll
                for (int r = 0; r < 4; ++r) {
                    int i = i0 + mt * 16 + q * 4 + r;
                    Kf[((((size_t)b * 128 + (i >> 5)) * 4 + (n >> 3)) * 32 + (i & 31)) * 8 + (n & 7)]
                        = (_Float16)(acc[mt][nt][r] + bias);
                }
        } else if (n < 64) {
            int n2 = n - 32;
#pragma unroll
            for (int mt = 0; mt < 4; ++mt)
#pragma unroll
                for (int r = 0; r < 4; ++r) {
                    int j = i0 + mt * 16 + q * 4 + r;
                    Qf[((((size_t)b * 128 + (j >> 5)) * 4 + (n2 >> 3)) * 32 + (j & 31)) * 8 + (n2 & 7)]
                        = (_Float16)(acc[mt][nt][r] + bias);
                }
        } else {
            int c = n - 64;
#pragma unroll
            for (int mt = 0; mt < 4; ++mt) {
                int ib = (i0 >> 4) + mt;
                half4 v4;
#pragma unroll
                for (int r = 0; r < 4; ++r) v4[r] = (_Float16)(acc[mt][nt][r] + bias);
                *(half4*)&Vf[(((size_t)b * 256 + ib) * 256 + c) * 16 + q * 4] = v4;
            }
        }
    }
}

// ---------------- K2: fused attention v5 ------------------------------------
// v4 dataflow (512 thr, j-tile 64, grid 512 = 2 blk/CU, 1 barrier/iter) plus:
//  - V register double-buffer, prefetch distance = 1 full iteration
//  - strength-reduced addressing (per-iter constant pointer bumps, imm offsets)
//  - unroll-by-2 so Ps ping-pong offsets are immediates
#define PS_BUF 4608  /* halfs per Ps buffer */

#define ATTN_STEP(IT, VCUR, VNXT, ROFF, WOFF)                                     \
    {                                                                             \
        if ((IT) < 63) {                                                          \
            _Pragma("unroll")                                                     \
            for (int ct = 0; ct < 2; ++ct) {                                      \
                VNXT[ct * 2 + 0] = *(const half8*)(pV0 + ct * 256);               \
                VNXT[ct * 2 + 1] = *(const half8*)(pV1 + ct * 256);               \
            }                                                                     \
            pV0 += 16384; pV1 += 16384;                                           \
            aKn0 = *(const half8*)(pK);                                           \
            aKn1 = *(const half8*)(pK + 128);                                     \
            pK += 2048;                                                           \
        }                                                                         \
        _Pragma("unroll")                                                         \
        for (int kk = 0; kk < 2; ++kk) {                                          \
            half8 bfr[4];                                                         \
            _Pragma("unroll")                                                     \
            for (int jt = 0; jt < 4; ++jt)                                        \
                bfr[jt] = *(const half8*)&PsF[psr + (ROFF) + jt * 1152 + kk * 32];\
            _Pragma("unroll")                                                     \
            for (int ct = 0; ct < 2; ++ct)                                        \
                _Pragma("unroll")                                                 \
                for (int jt = 0; jt < 4; ++jt)                                    \
                    acc[ct][jt] = __builtin_amdgcn_mfma_f32_16x16x32_f16(         \
                        VCUR[ct * 2 + kk], bfr[jt], acc[ct][jt], 0, 0, 0);        \
        }                                                                         \
        if ((IT) < 63) {                                                          \
            _Pragma("unroll")                                                     \
            for (int itl = 0; itl < 2; ++itl) {                                   \
                floatx4 s = __builtin_amdgcn_mfma_f32_16x16x32_f16(               \
                    itl ? aKn1 : aKn0, bq, (floatx4){0.f, 0.f, 0.f, 0.f}, 0, 0, 0);\
                float p0 = exp2f(s[0] * LOG2E + NSHIFT_L2E);                      \
                float p1 = exp2f(s[1] * LOG2E + NSHIFT_L2E);                      \
                float p2 = exp2f(s[2] * LOG2E + NSHIFT_L2E);                      \
                float p3 = exp2f(s[3] * LOG2E + NSHIFT_L2E);                      \
                lacc += (p0 + p1) + (p2 + p3);                                    \
                half4 ph;                                                         \
                ph[0] = (_Float16)p0; ph[1] = (_Float16)p1;                       \
                ph[2] = (_Float16)p2; ph[3] = (_Float16)p3;                       \
                *(half4*)&PsF[psw + (WOFF) + itl * 16] = ph;                      \
            }                                                                     \
        }                                                                         \
        __syncthreads();                                                          \
    }

__global__ __launch_bounds__(512, 4) void k_attn(const _Float16* __restrict__ Kf,
                                                 const _Float16* __restrict__ Qf,
                                                 const _Float16* __restrict__ Vf,
                                                 const float* __restrict__ x,
                                                 const float* __restrict__ gptr,
                                                 float* __restrict__ out) {
    __shared__ _Float16 PsF[2 * PS_BUF] __attribute__((aligned(16)));  // 18,432 B
    __shared__ float Lp[2][64];
    int id = blockIdx.x;
    int b  = id & 7;            // XCD-local batch
    int j0 = (id >> 3) * 64;
    int t = threadIdx.x;
    int w = t >> 6, lane = t & 63, col = lane & 15, q = lane >> 4;
    int jts = w & 3, ihs = w >> 2;   // S role
    int cw  = w * 32;                // PV c-strip
    const _Float16* Kfb = Kf + (size_t)b * 131072;
    const _Float16* Qfb = Qf + (size_t)b * 131072;
    const _Float16* Vfb = Vf + (size_t)b * 1048576;
    // ---- per-lane invariant pointers / offsets
    const _Float16* pK  = Kfb + ((ihs * 4 + q) * 32 + col) * 8;          // +it*2048, itl imm 128
    const _Float16* pV0 = Vfb + ((q >> 1) * 256 + cw + col) * 16 + (q & 1) * 8;  // +it*16384
    const _Float16* pV1 = pV0 + 8192;                                    // kk=1
    const int psw = (jts * 16 + col) * 72 + ihs * 32 + q * 4;            // + itl*16 + buf
    const int psr = col * 72 + q * 8;                                    // + jt*1152 + kk*32 + buf
    floatx4 acc[2][4];
#pragma unroll
    for (int ct = 0; ct < 2; ++ct)
#pragma unroll
        for (int jt = 0; jt < 4; ++jt) acc[ct][jt] = (floatx4){0.f, 0.f, 0.f, 0.f};
    float lacc = 0.f;
    half8 vA[4], vB[4], aKn0, aKn1;
    // ---- prologue: issue V(0), K(0), Q; compute S(0) -> buf0
#pragma unroll
    for (int ct = 0; ct < 2; ++ct) {
        vA[ct * 2 + 0] = *(const half8*)(pV0 + ct * 256);
        vA[ct * 2 + 1] = *(const half8*)(pV1 + ct * 256);
    }
    pV0 += 16384; pV1 += 16384;
    aKn0 = *(const half8*)(pK);
    aKn1 = *(const half8*)(pK + 128);
    pK += 2048;
    int jj = j0 + jts * 16;
    half8 bq = *(const half8*)&Qfb[(((jj >> 5) * 4 + q) * 32 + ((jj & 31) + col)) * 8];
#pragma unroll
    for (int itl = 0; itl < 2; ++itl) {
        floatx4 s = __builtin_amdgcn_mfma_f32_16x16x32_f16(itl ? aKn1 : aKn0, bq,
                                                           (floatx4){0.f, 0.f, 0.f, 0.f}, 0, 0, 0);
        float p0 = exp2f(s[0] * LOG2E + NSHIFT_L2E);
        float p1 = exp2f(s[1] * LOG2E + NSHIFT_L2E);
        float p2 = exp2f(s[2] * LOG2E + NSHIFT_L2E);
        float p3 = exp2f(s[3] * LOG2E + NSHIFT_L2E);
        lacc += (p0 + p1) + (p2 + p3);
        half4 ph;
        ph[0] = (_Float16)p0; ph[1] = (_Float16)p1;
        ph[2] = (_Float16)p2; ph[3] = (_Float16)p3;
        *(half4*)&PsF[psw + itl * 16] = ph;
    }
    __syncthreads();
    // ---- main loop: 64 iters, unrolled by 2 (one barrier per iter)
    for (int m = 0; m < 32; ++m) {
        int it = m * 2;
        ATTN_STEP(it,     vA, vB, 0,      PS_BUF)
        ATTN_STEP(it + 1, vB, vA, PS_BUF, 0)
    }
    // ---- l finalize
    lacc += __shfl_xor(lacc, 16, 64);
    lacc += __shfl_xor(lacc, 32, 64);
    if (lane < 16) Lp[ihs][jts * 16 + lane] = lacc;
    __syncthreads();
    float gamma = gptr[0];
    const float* xb = x + (size_t)b * C_ * N_;
    float* ob = out + (size_t)b * C_ * N_;
#pragma unroll
    for (int jt = 0; jt < 4; ++jt) {
        int jl = jt * 16 + col;
        float li = 1.0f / (Lp[0][jl] + Lp[1][jl]);
        int j = j0 + jl;
#pragma unroll
        for (int ct = 0; ct < 2; ++ct)
#pragma unroll
            for (int r = 0; r < 4; ++r) {
                int c = cw + ct * 16 + q * 4 + r;
                size_t off = (size_t)c * N_ + j;
                ob[off] = gamma * acc[ct][jt][r] * li + xb[off];
            }
    }
}

extern "C" void kernel_launch(void* const* d_in, const int* in_sizes, int n_in,
                              void* d_out, int out_size, void* d_ws, size_t ws_size,
                              hipStream_t stream) {
    const float* x  = (const float*)d_in[0];
    const float* wq = (const float*)d_in[1];
    const float* bq = (const float*)d_in[2];
    const float* wk = (const float*)d_in[3];
    const float* bk = (const float*)d_in[4];
    const float* wv = (const float*)d_in[5];
    const float* bv = (const float*)d_in[6];
    const float* gm = (const float*)d_in[7];
    float* out = (float*)d_out;
    char* ws = (char*)d_ws;
    // workspace layout (~21.1 MB)
    _Float16* Vf  = (_Float16*)ws;                    // 16,777,216 B
    _Float16* Kf  = (_Float16*)(ws + 16777216);       //  2,097,152 B
    _Float16* Qf  = (_Float16*)(ws + 18874368);       //  2,097,152 B
    _Float16* Whf = (_Float16*)(ws + 20971520);       //    163,840 B
    float*    Bh  = (float*)(ws + 21135360);          //      1,280 B

    k_wprep<<<dim3(320), 256, 0, stream>>>(wq, bq, wk, bk, wv, bv, Whf, Bh);
    k_proj<<<dim3(512), 256, 0, stream>>>(x, Whf, Bh, Kf, Qf, Vf);
    k_attn<<<dim3(512), 512, 0, stream>>>(Kf, Qf, Vf, x, gm, out);
}